// Round 5
// baseline (332.035 us; speedup 1.0000x reference)
//
#include <hip/hip_runtime.h>
#include <hip/hip_bf16.h>
#include <string.h>

#define NN 100000
#define NE 1600000
#define INF_ 128
#define OC 128   // NHEAD*OUT_F
#define NH 4
#define ALPHA 0.2f
#define NBLK ((NN + 1023) / 1024)   // 98 scan blocks
#define LDA 272                      // LDS row stride in bytes (256 + 16 pad)
#define ECAP 64                      // per-wave cached edges in k_agg

typedef __bf16 bf16x8 __attribute__((ext_vector_type(8)));
typedef float f32x4 __attribute__((ext_vector_type(4)));

__device__ __forceinline__ float lrelu(float x) {
    return x > 0.0f ? x : ALPHA * x;
}
__device__ __forceinline__ unsigned short f2bf(float f) {
    __hip_bfloat16 b = __float2bfloat16(f);
    unsigned short u; memcpy(&u, &b, 2); return u;
}

// MFMA GEMM: h = x @ W, bf16 inputs (converted on the fly), fp32 accum, bf16 out.
__global__ __launch_bounds__(256) void k_gemm(
    const float* __restrict__ x, const float* __restrict__ W,
    __hip_bfloat16* __restrict__ hb) {
    __shared__ __align__(16) char sA[64 * LDA];    // x tile, bf16 [64][128]
    __shared__ __align__(16) char sB[128 * LDA];   // Wt, bf16 [col][k]
    const int tid = threadIdx.x;
    const int rowBase = blockIdx.x * 64;

    {
        union { uint2 d; unsigned short u[4]; } pk;
        for (int j = 0; j < 8; ++j) {
            const int i4 = tid + j * 256;
            const int r = i4 >> 5, c4 = i4 & 31;
            const int g = rowBase + r;
            float4 v = make_float4(0.f, 0.f, 0.f, 0.f);
            if (g < NN) v = *(const float4*)&x[(size_t)g * INF_ + c4 * 4];
            pk.u[0] = f2bf(v.x); pk.u[1] = f2bf(v.y);
            pk.u[2] = f2bf(v.z); pk.u[3] = f2bf(v.w);
            *(uint2*)(sA + r * LDA + c4 * 8) = pk.d;
        }
    }
    {
        const int c = tid & 127, kh = tid >> 7;
        union { uint4 q; unsigned short u[8]; } pk;
        for (int kb = 0; kb < 8; ++kb) {
            const int k0 = kh * 64 + kb * 8;
#pragma unroll
            for (int j = 0; j < 8; ++j)
                pk.u[j] = f2bf(W[(size_t)(k0 + j) * OC + c]);
            *(uint4*)(sB + c * LDA + k0 * 2) = pk.q;
        }
    }
    __syncthreads();

    const int lane = tid & 63;
    const int w = tid >> 6;
    const int arow = w * 16 + (lane & 15);
    const int koff = (lane >> 4) * 16;

    f32x4 acc[8];
#pragma unroll
    for (int n = 0; n < 8; ++n) acc[n] = (f32x4){0.f, 0.f, 0.f, 0.f};

#pragma unroll
    for (int kk = 0; kk < 4; ++kk) {
        const bf16x8 a = *(const bf16x8*)(sA + arow * LDA + kk * 64 + koff);
#pragma unroll
        for (int n = 0; n < 8; ++n) {
            const int brow = n * 16 + (lane & 15);
            const bf16x8 b = *(const bf16x8*)(sB + brow * LDA + kk * 64 + koff);
            acc[n] = __builtin_amdgcn_mfma_f32_16x16x32_bf16(a, b, acc[n], 0, 0, 0);
        }
    }

    const int rbase = rowBase + w * 16 + (lane >> 4) * 4;
#pragma unroll
    for (int n = 0; n < 8; ++n) {
        const int col = n * 16 + (lane & 15);
#pragma unroll
        for (int r = 0; r < 4; ++r) {
            const int row = rbase + r;
            if (row < NN) hb[(size_t)row * OC + col] = __float2bfloat16(acc[n][r]);
        }
    }
}

// Per-(node, head) attention halves from bf16 h.
__global__ __launch_bounds__(256) void k_att(
    const __hip_bfloat16* __restrict__ hb,
    const float* __restrict__ a_l, const float* __restrict__ a_r,
    float* __restrict__ al, float* __restrict__ ar) {
    const int t = blockIdx.x * 256 + threadIdx.x;
    if (t >= NN * NH) return;
    const int n = t >> 2, hd = t & 3;
    const uint4* hp = (const uint4*)((const char*)hb + (size_t)n * 256 + hd * 64);
    const float* alc = a_l + hd * 32;
    const float* arc = a_r + hd * 32;
    float sl = 0.f, sr = 0.f;
#pragma unroll
    for (int q = 0; q < 4; ++q) {
        const uint4 v = hp[q];
        const unsigned uu[4] = {v.x, v.y, v.z, v.w};
#pragma unroll
        for (int i = 0; i < 4; ++i) {
            const int k = q * 8 + i * 2;
            const float lo = __uint_as_float(uu[i] << 16);
            const float hi = __uint_as_float(uu[i] & 0xffff0000u);
            sl += lo * alc[k] + hi * alc[k + 1];
            sr += lo * arc[k] + hi * arc[k + 1];
        }
    }
    al[t] = sl;
    ar[t] = sr;
}

// Histogram of destination degree.
__global__ __launch_bounds__(256) void k_hist(
    const int* __restrict__ row, int* __restrict__ deg) {
    const int ed = blockIdx.x * 256 + threadIdx.x;
    if (ed >= NE) return;
    atomicAdd(&deg[row[ed]], 1);
}

// Scan phase A: per-block (1024 elems) sums.
__global__ __launch_bounds__(256) void k_bsum(
    const int* __restrict__ deg, int* __restrict__ bsum) {
    __shared__ int red[256];
    const int b = blockIdx.x, t = threadIdx.x;
    const int base = b * 1024 + t * 4;
    int s = 0;
#pragma unroll
    for (int i = 0; i < 4; ++i) {
        int idx = base + i;
        if (idx < NN) s += deg[idx];
    }
    red[t] = s;
    __syncthreads();
    for (int o = 128; o > 0; o >>= 1) {
        if (t < o) red[t] += red[t + o];
        __syncthreads();
    }
    if (t == 0) bsum[b] = red[0];
}

// Scan phase B: exclusive scan of block sums.
__global__ void k_bscan(const int* __restrict__ bsum, int* __restrict__ bbase,
                        int* __restrict__ offs) {
    if (threadIdx.x == 0) {
        int acc = 0;
        for (int i = 0; i < NBLK; ++i) { bbase[i] = acc; acc += bsum[i]; }
        offs[NN] = NE;
    }
}

// Scan phase C: final exclusive offsets; cursor gets a working copy.
__global__ __launch_bounds__(256) void k_offs(
    const int* __restrict__ deg, const int* __restrict__ bbase,
    int* __restrict__ offs, int* __restrict__ cursor) {
    __shared__ int ts[256];
    const int b = blockIdx.x, t = threadIdx.x;
    const int base = b * 1024 + t * 4;
    int v[4];
    int s = 0;
#pragma unroll
    for (int i = 0; i < 4; ++i) {
        int idx = base + i;
        v[i] = (idx < NN) ? deg[idx] : 0;
        s += v[i];
    }
    ts[t] = s;
    __syncthreads();
    for (int o = 1; o < 256; o <<= 1) {
        int add = (t >= o) ? ts[t - o] : 0;
        __syncthreads();
        ts[t] += add;
        __syncthreads();
    }
    int ex = ts[t] - s + bbase[b];
#pragma unroll
    for (int i = 0; i < 4; ++i) {
        int idx = base + i;
        if (idx < NN) { offs[idx] = ex; cursor[idx] = ex; }
        ex += v[i];
    }
}

// Scatter: only the source column index, 4B per edge.
__global__ __launch_bounds__(256) void k_scatter(
    const int* __restrict__ row, const int* __restrict__ col,
    int* __restrict__ cursor, int* __restrict__ cols_s) {
    const int ed = blockIdx.x * 256 + threadIdx.x;
    if (ed >= NE) return;
    const int r = row[ed];
    const int pos = atomicAdd(&cursor[r], 1);
    cols_s[pos] = col[ed];
}

// Fused score + softmax + aggregation: one wave per destination node.
__global__ __launch_bounds__(256) void k_agg(
    const int* __restrict__ offs, const int* __restrict__ cols_s,
    const float* __restrict__ al, const float* __restrict__ ar,
    const __hip_bfloat16* __restrict__ hb, float* __restrict__ out) {
    __shared__ float eC[4][ECAP * NH];   // 4 KB
    const int w = threadIdx.x >> 6;
    const int lane = threadIdx.x & 63;
    const int node = blockIdx.x * 4 + w;
    if (node >= NN) return;
    const int start = offs[node], end = offs[node + 1];
    const size_t loff = (size_t)(lane * 2);
    if (start == end) {
        *(float2*)&out[(size_t)node * OC + loff] = make_float2(0.f, 0.f);
        return;
    }
    const int sh = lane & 3;   // head this lane reduces
    const int se = lane >> 2;  // edge slot within 16-edge sweep
    const float al_sh = al[node * NH + sh];

    // Sweep 1: compute scores, cache in LDS, per-lane max.
    float m = -1e30f;
    for (int k = start + se; k < end; k += 16) {
        const int c = cols_s[k];
        const float e = lrelu(al_sh + ar[c * NH + sh]);
        const int idx = k - start;
        if (idx < ECAP) eC[w][idx * NH + sh] = e;
        m = fmaxf(m, e);
    }
#pragma unroll
    for (int msk = 4; msk <= 32; msk <<= 1) m = fmaxf(m, __shfl_xor(m, msk));

    // Sweep 2: sum of exp.
    float ssum = 0.f;
    for (int k = start + se; k < end; k += 16) {
        const int idx = k - start;
        float e;
        if (idx < ECAP) e = eC[w][idx * NH + sh];
        else { const int c = cols_s[k]; e = lrelu(al_sh + ar[c * NH + sh]); }
        ssum += __expf(e - m);
    }
#pragma unroll
    for (int msk = 4; msk <= 32; msk <<= 1) ssum += __shfl_xor(ssum, msk);

    const int hd = lane >> 4;              // head this lane accumulates
    const float mh  = __shfl(m, hd);       // lanes 0..3 hold heads 0..3
    const float inv = 1.0f / __shfl(ssum, hd);
    const float al_hd = al[node * NH + hd];

    // Phase 2: gather-accumulate, 4 edges in flight, scores from LDS.
    float accx = 0.f, accy = 0.f;
    const int mid = min(end, start + ECAP);
    int k = start;
    for (; k + 4 <= mid; k += 4) {
        const int c0 = cols_s[k + 0], c1 = cols_s[k + 1];
        const int c2 = cols_s[k + 2], c3 = cols_s[k + 3];
        const float e0 = eC[w][(k + 0 - start) * NH + hd];
        const float e1 = eC[w][(k + 1 - start) * NH + hd];
        const float e2 = eC[w][(k + 2 - start) * NH + hd];
        const float e3 = eC[w][(k + 3 - start) * NH + hd];
        const unsigned v0 = *(const unsigned*)&hb[(size_t)c0 * OC + loff];
        const unsigned v1 = *(const unsigned*)&hb[(size_t)c1 * OC + loff];
        const unsigned v2 = *(const unsigned*)&hb[(size_t)c2 * OC + loff];
        const unsigned v3 = *(const unsigned*)&hb[(size_t)c3 * OC + loff];
        const float p0 = __expf(e0 - mh) * inv;
        const float p1 = __expf(e1 - mh) * inv;
        const float p2 = __expf(e2 - mh) * inv;
        const float p3 = __expf(e3 - mh) * inv;
        accx += p0 * __uint_as_float(v0 << 16);
        accy += p0 * __uint_as_float(v0 & 0xffff0000u);
        accx += p1 * __uint_as_float(v1 << 16);
        accy += p1 * __uint_as_float(v1 & 0xffff0000u);
        accx += p2 * __uint_as_float(v2 << 16);
        accy += p2 * __uint_as_float(v2 & 0xffff0000u);
        accx += p3 * __uint_as_float(v3 << 16);
        accy += p3 * __uint_as_float(v3 & 0xffff0000u);
    }
    for (; k < mid; ++k) {
        const int c = cols_s[k];
        const float e = eC[w][(k - start) * NH + hd];
        const float p = __expf(e - mh) * inv;
        const unsigned v = *(const unsigned*)&hb[(size_t)c * OC + loff];
        accx += p * __uint_as_float(v << 16);
        accy += p * __uint_as_float(v & 0xffff0000u);
    }
    for (; k < end; ++k) {   // ultra-rare deg > ECAP tail: recompute
        const int c = cols_s[k];
        const float e = lrelu(al_hd + ar[c * NH + hd]);
        const float p = __expf(e - mh) * inv;
        const unsigned v = *(const unsigned*)&hb[(size_t)c * OC + loff];
        accx += p * __uint_as_float(v << 16);
        accy += p * __uint_as_float(v & 0xffff0000u);
    }
    float2 o; o.x = accx; o.y = accy;
    *(float2*)&out[(size_t)node * OC + loff] = o;
}

extern "C" void kernel_launch(void* const* d_in, const int* in_sizes, int n_in,
                              void* d_out, int out_size, void* d_ws, size_t ws_size,
                              hipStream_t stream) {
    const float* x    = (const float*)d_in[0];
    const int*   ei   = (const int*)d_in[1];    // [2, NE]
    const float* W    = (const float*)d_in[2];
    const float* a_l  = (const float*)d_in[3];
    const float* a_r  = (const float*)d_in[4];
    float* out = (float*)d_out;

    const int* row = ei;         // destination
    const int* col = ei + NE;    // source

    char* ws = (char*)d_ws;
    __hip_bfloat16* hb = (__hip_bfloat16*)ws;   ws += (size_t)NN * OC * 2;   // 25.6 MB
    float* al     = (float*)ws;                 ws += (size_t)NN * NH * 4;
    float* ar     = (float*)ws;                 ws += (size_t)NN * NH * 4;
    int*   cols_s = (int*)ws;                   ws += (size_t)NE * 4;        // 6.4 MB
    int*   deg    = (int*)ws;                   ws += (size_t)NN * 4;
    int*   cursor = (int*)ws;                   ws += (size_t)NN * 4;
    int*   offs   = (int*)ws;                   ws += (size_t)(NN + 1) * 4;
    int*   bsum   = (int*)ws;                   ws += (size_t)NBLK * 4;
    int*   bbase  = (int*)ws;

    hipMemsetAsync(deg, 0, (size_t)NN * 4, stream);

    k_gemm<<<(NN + 63) / 64, 256, 0, stream>>>(x, W, hb);
    k_att<<<(NN * NH + 255) / 256, 256, 0, stream>>>(hb, a_l, a_r, al, ar);
    k_hist<<<(NE + 255) / 256, 256, 0, stream>>>(row, deg);
    k_bsum<<<NBLK, 256, 0, stream>>>(deg, bsum);
    k_bscan<<<1, 64, 0, stream>>>(bsum, bbase, offs);
    k_offs<<<NBLK, 256, 0, stream>>>(deg, bbase, offs, cursor);
    k_scatter<<<(NE + 255) / 256, 256, 0, stream>>>(row, col, cursor, cols_s);
    k_agg<<<(NN + 3) / 4, 256, 0, stream>>>(offs, cols_s, al, ar, hb, out);
}

// Round 6
// 203.499 us; speedup vs baseline: 1.6316x; 1.6316x over previous
//
#include <hip/hip_runtime.h>
#include <hip/hip_bf16.h>
#include <string.h>

#define NN 100000
#define NE 1600000
#define INF_ 128
#define OC 128   // NHEAD*OUT_F
#define NH 4
#define ALPHA 0.2f
#define LDA 272                      // GEMM LDS row stride in bytes
#define ECAP 64                      // per-wave cached edges in k_agg

#define BSH 9
#define BINW 512                     // nodes per bin
#define NBIN ((NN + BINW - 1) / BINW)   // 196
#define EPT 16                       // edges per thread, partition kernels
#define EPB (256 * EPT)              // 4096 edges per block
#define NPB1 ((NE + EPB - 1) / EPB)  // 391 blocks
#define CAP2 12288                   // LDS staging capacity in k_part2

typedef __bf16 bf16x8 __attribute__((ext_vector_type(8)));
typedef float f32x4 __attribute__((ext_vector_type(4)));

__device__ __forceinline__ float lrelu(float x) {
    return x > 0.0f ? x : ALPHA * x;
}
__device__ __forceinline__ unsigned short f2bf(float f) {
    __hip_bfloat16 b = __float2bfloat16(f);
    unsigned short u; memcpy(&u, &b, 2); return u;
}

// MFMA GEMM: h = x @ W, bf16 inputs (converted on the fly), fp32 accum, bf16 out.
__global__ __launch_bounds__(256) void k_gemm(
    const float* __restrict__ x, const float* __restrict__ W,
    __hip_bfloat16* __restrict__ hb) {
    __shared__ __align__(16) char sA[64 * LDA];    // x tile, bf16 [64][128]
    __shared__ __align__(16) char sB[128 * LDA];   // Wt, bf16 [col][k]
    const int tid = threadIdx.x;
    const int rowBase = blockIdx.x * 64;

    {
        union { uint2 d; unsigned short u[4]; } pk;
        for (int j = 0; j < 8; ++j) {
            const int i4 = tid + j * 256;
            const int r = i4 >> 5, c4 = i4 & 31;
            const int g = rowBase + r;
            float4 v = make_float4(0.f, 0.f, 0.f, 0.f);
            if (g < NN) v = *(const float4*)&x[(size_t)g * INF_ + c4 * 4];
            pk.u[0] = f2bf(v.x); pk.u[1] = f2bf(v.y);
            pk.u[2] = f2bf(v.z); pk.u[3] = f2bf(v.w);
            *(uint2*)(sA + r * LDA + c4 * 8) = pk.d;
        }
    }
    {
        const int c = tid & 127, kh = tid >> 7;
        union { uint4 q; unsigned short u[8]; } pk;
        for (int kb = 0; kb < 8; ++kb) {
            const int k0 = kh * 64 + kb * 8;
#pragma unroll
            for (int j = 0; j < 8; ++j)
                pk.u[j] = f2bf(W[(size_t)(k0 + j) * OC + c]);
            *(uint4*)(sB + c * LDA + k0 * 2) = pk.q;
        }
    }
    __syncthreads();

    const int lane = tid & 63;
    const int w = tid >> 6;
    const int arow = w * 16 + (lane & 15);
    const int koff = (lane >> 4) * 16;

    f32x4 acc[8];
#pragma unroll
    for (int n = 0; n < 8; ++n) acc[n] = (f32x4){0.f, 0.f, 0.f, 0.f};

#pragma unroll
    for (int kk = 0; kk < 4; ++kk) {
        const bf16x8 a = *(const bf16x8*)(sA + arow * LDA + kk * 64 + koff);
#pragma unroll
        for (int n = 0; n < 8; ++n) {
            const int brow = n * 16 + (lane & 15);
            const bf16x8 b = *(const bf16x8*)(sB + brow * LDA + kk * 64 + koff);
            acc[n] = __builtin_amdgcn_mfma_f32_16x16x32_bf16(a, b, acc[n], 0, 0, 0);
        }
    }

    const int rbase = rowBase + w * 16 + (lane >> 4) * 4;
#pragma unroll
    for (int n = 0; n < 8; ++n) {
        const int col = n * 16 + (lane & 15);
#pragma unroll
        for (int r = 0; r < 4; ++r) {
            const int row = rbase + r;
            if (row < NN) hb[(size_t)row * OC + col] = __float2bfloat16(acc[n][r]);
        }
    }
}

// Per-(node, head) attention halves from bf16 h.
__global__ __launch_bounds__(256) void k_att(
    const __hip_bfloat16* __restrict__ hb,
    const float* __restrict__ a_l, const float* __restrict__ a_r,
    float* __restrict__ al, float* __restrict__ ar) {
    const int t = blockIdx.x * 256 + threadIdx.x;
    if (t >= NN * NH) return;
    const int n = t >> 2, hd = t & 3;
    const uint4* hp = (const uint4*)((const char*)hb + (size_t)n * 256 + hd * 64);
    const float* alc = a_l + hd * 32;
    const float* arc = a_r + hd * 32;
    float sl = 0.f, sr = 0.f;
#pragma unroll
    for (int q = 0; q < 4; ++q) {
        const uint4 v = hp[q];
        const unsigned uu[4] = {v.x, v.y, v.z, v.w};
#pragma unroll
        for (int i = 0; i < 4; ++i) {
            const int k = q * 8 + i * 2;
            const float lo = __uint_as_float(uu[i] << 16);
            const float hi = __uint_as_float(uu[i] & 0xffff0000u);
            sl += lo * alc[k] + hi * alc[k + 1];
            sr += lo * arc[k] + hi * arc[k + 1];
        }
    }
    al[t] = sl;
    ar[t] = sr;
}

// Per-bin edge counts (LDS pre-aggregated).
__global__ __launch_bounds__(256) void k_binhist(
    const int* __restrict__ row, int* __restrict__ bincnt) {
    __shared__ int h[NBIN];
    const int t = threadIdx.x;
    for (int i = t; i < NBIN; i += 256) h[i] = 0;
    __syncthreads();
    const int base = blockIdx.x * EPB;
    for (int i = 0; i < EPT; ++i) {
        const int e = base + t + i * 256;
        if (e < NE) atomicAdd(&h[row[e] >> BSH], 1);
    }
    __syncthreads();
    for (int i = t; i < NBIN; i += 256)
        if (h[i]) atomicAdd(&bincnt[i], h[i]);
}

// Serial scan of bin counts -> binoffs, bincur; also offs[NN].
__global__ void k_binscan(const int* __restrict__ bincnt,
                          int* __restrict__ binoffs, int* __restrict__ bincur,
                          int* __restrict__ offs) {
    if (threadIdx.x == 0) {
        int acc = 0;
        for (int i = 0; i < NBIN; ++i) {
            binoffs[i] = acc; bincur[i] = acc; acc += bincnt[i];
        }
        binoffs[NBIN] = acc;   // == NE
        offs[NN] = NE;
    }
}

// Coarse partition: edges -> bin-grouped packed words ((r&511)<<17 | c).
__global__ __launch_bounds__(256) void k_part1(
    const int* __restrict__ row, const int* __restrict__ col,
    int* __restrict__ bincur, unsigned* __restrict__ tmp) {
    __shared__ int h[NBIN], gbase[NBIN], lcur[NBIN];
    const int t = threadIdx.x;
    for (int i = t; i < NBIN; i += 256) { h[i] = 0; lcur[i] = 0; }
    __syncthreads();

    const int e0 = blockIdx.x * EPB + t * EPT;
    int r[EPT], c[EPT];
    if (e0 + EPT <= NE) {
#pragma unroll
        for (int q = 0; q < EPT / 4; ++q) {
            const int4 rv = *(const int4*)&row[e0 + q * 4];
            const int4 cv = *(const int4*)&col[e0 + q * 4];
            r[q*4+0] = rv.x; r[q*4+1] = rv.y; r[q*4+2] = rv.z; r[q*4+3] = rv.w;
            c[q*4+0] = cv.x; c[q*4+1] = cv.y; c[q*4+2] = cv.z; c[q*4+3] = cv.w;
        }
    } else {
#pragma unroll
        for (int i = 0; i < EPT; ++i) {
            const int e = e0 + i;
            r[i] = (e < NE) ? row[e] : -1;
            c[i] = (e < NE) ? col[e] : 0;
        }
    }
#pragma unroll
    for (int i = 0; i < EPT; ++i)
        if (r[i] >= 0) atomicAdd(&h[r[i] >> BSH], 1);
    __syncthreads();
    for (int i = t; i < NBIN; i += 256)
        if (h[i]) gbase[i] = atomicAdd(&bincur[i], h[i]);
    __syncthreads();
#pragma unroll
    for (int i = 0; i < EPT; ++i) {
        if (r[i] < 0) continue;
        const int b = r[i] >> BSH;
        const int pos = atomicAdd(&lcur[b], 1);
        tmp[gbase[b] + pos] =
            ((unsigned)(r[i] & (BINW - 1)) << 17) | (unsigned)c[i];
    }
}

// Fine partition: one block per bin; emits node-sorted cols_s + per-node offs.
__global__ __launch_bounds__(256) void k_part2(
    const unsigned* __restrict__ tmp, const int* __restrict__ binoffs,
    int* __restrict__ offs, int* __restrict__ cols_s) {
    __shared__ unsigned stage[CAP2];          // 48 KB
    __shared__ int h[BINW], ps[256], cur[BINW];
    const int b = blockIdx.x, t = threadIdx.x;
    const int gs = binoffs[b], ge = binoffs[b + 1];
    const int cnt = ge - gs;
    for (int i = t; i < BINW; i += 256) h[i] = 0;
    __syncthreads();
    for (int j = t; j < cnt; j += 256) {
        const unsigned p = tmp[gs + j];
        if (j < CAP2) stage[j] = p;
        atomicAdd(&h[p >> 17], 1);
    }
    __syncthreads();
    // exclusive scan over 512 via 256 pair-sums
    const int a0 = h[2 * t], a1 = h[2 * t + 1];
    ps[t] = a0 + a1;
    __syncthreads();
    for (int o = 1; o < 256; o <<= 1) {
        const int add = (t >= o) ? ps[t - o] : 0;
        __syncthreads();
        ps[t] += add;
        __syncthreads();
    }
    const int ex = ps[t] - a0 - a1 + gs;
    cur[2 * t] = ex;
    cur[2 * t + 1] = ex + a0;
    const int node0 = b * BINW;
    if (node0 + 2 * t < NN)     offs[node0 + 2 * t]     = ex;
    if (node0 + 2 * t + 1 < NN) offs[node0 + 2 * t + 1] = ex + a0;
    __syncthreads();
    for (int j = t; j < cnt; j += 256) {
        const unsigned p = (j < CAP2) ? stage[j] : tmp[gs + j];
        const int pos = atomicAdd(&cur[p >> 17], 1);
        cols_s[pos] = (int)(p & 0x1FFFFu);
    }
}

// Fused score + softmax + aggregation: one wave per destination node.
__global__ __launch_bounds__(256) void k_agg(
    const int* __restrict__ offs, const int* __restrict__ cols_s,
    const float* __restrict__ al, const float* __restrict__ ar,
    const __hip_bfloat16* __restrict__ hb, float* __restrict__ out) {
    __shared__ float eC[4][ECAP * NH];   // 4 KB
    const int w = threadIdx.x >> 6;
    const int lane = threadIdx.x & 63;
    const int node = blockIdx.x * 4 + w;
    if (node >= NN) return;
    const int start = offs[node], end = offs[node + 1];
    const size_t loff = (size_t)(lane * 2);
    if (start == end) {
        *(float2*)&out[(size_t)node * OC + loff] = make_float2(0.f, 0.f);
        return;
    }
    const int sh = lane & 3;
    const int se = lane >> 2;
    const float al_sh = al[node * NH + sh];

    float m = -1e30f;
    for (int k = start + se; k < end; k += 16) {
        const int c = cols_s[k];
        const float e = lrelu(al_sh + ar[c * NH + sh]);
        const int idx = k - start;
        if (idx < ECAP) eC[w][idx * NH + sh] = e;
        m = fmaxf(m, e);
    }
#pragma unroll
    for (int msk = 4; msk <= 32; msk <<= 1) m = fmaxf(m, __shfl_xor(m, msk));

    float ssum = 0.f;
    for (int k = start + se; k < end; k += 16) {
        const int idx = k - start;
        float e;
        if (idx < ECAP) e = eC[w][idx * NH + sh];
        else { const int c = cols_s[k]; e = lrelu(al_sh + ar[c * NH + sh]); }
        ssum += __expf(e - m);
    }
#pragma unroll
    for (int msk = 4; msk <= 32; msk <<= 1) ssum += __shfl_xor(ssum, msk);

    const int hd = lane >> 4;
    const float mh  = __shfl(m, hd);
    const float inv = 1.0f / __shfl(ssum, hd);
    const float al_hd = al[node * NH + hd];

    float accx = 0.f, accy = 0.f;
    const int mid = min(end, start + ECAP);
    int k = start;
    for (; k + 4 <= mid; k += 4) {
        const int c0 = cols_s[k + 0], c1 = cols_s[k + 1];
        const int c2 = cols_s[k + 2], c3 = cols_s[k + 3];
        const float e0 = eC[w][(k + 0 - start) * NH + hd];
        const float e1 = eC[w][(k + 1 - start) * NH + hd];
        const float e2 = eC[w][(k + 2 - start) * NH + hd];
        const float e3 = eC[w][(k + 3 - start) * NH + hd];
        const unsigned v0 = *(const unsigned*)&hb[(size_t)c0 * OC + loff];
        const unsigned v1 = *(const unsigned*)&hb[(size_t)c1 * OC + loff];
        const unsigned v2 = *(const unsigned*)&hb[(size_t)c2 * OC + loff];
        const unsigned v3 = *(const unsigned*)&hb[(size_t)c3 * OC + loff];
        const float p0 = __expf(e0 - mh) * inv;
        const float p1 = __expf(e1 - mh) * inv;
        const float p2 = __expf(e2 - mh) * inv;
        const float p3 = __expf(e3 - mh) * inv;
        accx += p0 * __uint_as_float(v0 << 16);
        accy += p0 * __uint_as_float(v0 & 0xffff0000u);
        accx += p1 * __uint_as_float(v1 << 16);
        accy += p1 * __uint_as_float(v1 & 0xffff0000u);
        accx += p2 * __uint_as_float(v2 << 16);
        accy += p2 * __uint_as_float(v2 & 0xffff0000u);
        accx += p3 * __uint_as_float(v3 << 16);
        accy += p3 * __uint_as_float(v3 & 0xffff0000u);
    }
    for (; k < mid; ++k) {
        const int c = cols_s[k];
        const float e = eC[w][(k - start) * NH + hd];
        const float p = __expf(e - mh) * inv;
        const unsigned v = *(const unsigned*)&hb[(size_t)c * OC + loff];
        accx += p * __uint_as_float(v << 16);
        accy += p * __uint_as_float(v & 0xffff0000u);
    }
    for (; k < end; ++k) {
        const int c = cols_s[k];
        const float e = lrelu(al_hd + ar[c * NH + hd]);
        const float p = __expf(e - mh) * inv;
        const unsigned v = *(const unsigned*)&hb[(size_t)c * OC + loff];
        accx += p * __uint_as_float(v << 16);
        accy += p * __uint_as_float(v & 0xffff0000u);
    }
    float2 o; o.x = accx; o.y = accy;
    *(float2*)&out[(size_t)node * OC + loff] = o;
}

extern "C" void kernel_launch(void* const* d_in, const int* in_sizes, int n_in,
                              void* d_out, int out_size, void* d_ws, size_t ws_size,
                              hipStream_t stream) {
    const float* x    = (const float*)d_in[0];
    const int*   ei   = (const int*)d_in[1];    // [2, NE]
    const float* W    = (const float*)d_in[2];
    const float* a_l  = (const float*)d_in[3];
    const float* a_r  = (const float*)d_in[4];
    float* out = (float*)d_out;

    const int* row = ei;         // destination
    const int* col = ei + NE;    // source

    char* ws = (char*)d_ws;
    __hip_bfloat16* hb = (__hip_bfloat16*)ws;   ws += (size_t)NN * OC * 2;   // 25.6 MB
    float*    al      = (float*)ws;             ws += (size_t)NN * NH * 4;
    float*    ar      = (float*)ws;             ws += (size_t)NN * NH * 4;
    int*      cols_s  = (int*)ws;               ws += (size_t)NE * 4;        // 6.4 MB
    unsigned* tmp     = (unsigned*)ws;          ws += (size_t)NE * 4;        // 6.4 MB
    int*      offs    = (int*)ws;               ws += (size_t)(NN + 1) * 4;
    int*      bincnt  = (int*)ws;               ws += (size_t)(NBIN + 1) * 4;
    int*      binoffs = (int*)ws;               ws += (size_t)(NBIN + 1) * 4;
    int*      bincur  = (int*)ws;               ws += (size_t)NBIN * 4;

    hipMemsetAsync(bincnt, 0, (size_t)NBIN * 4, stream);

    k_gemm<<<(NN + 63) / 64, 256, 0, stream>>>(x, W, hb);
    k_att<<<(NN * NH + 255) / 256, 256, 0, stream>>>(hb, a_l, a_r, al, ar);
    k_binhist<<<NPB1, 256, 0, stream>>>(row, bincnt);
    k_binscan<<<1, 64, 0, stream>>>(bincnt, binoffs, bincur, offs);
    k_part1<<<NPB1, 256, 0, stream>>>(row, col, bincur, tmp);
    k_part2<<<NBIN, 256, 0, stream>>>(tmp, binoffs, offs, cols_s);
    k_agg<<<(NN + 3) / 4, 256, 0, stream>>>(offs, cols_s, al, ar, hb, out);
}

// Round 7
// 192.533 us; speedup vs baseline: 1.7246x; 1.0570x over previous
//
#include <hip/hip_runtime.h>
#include <hip/hip_bf16.h>
#include <string.h>

#define NN 100000
#define NE 1600000
#define INF_ 128
#define OC 128   // NHEAD*OUT_F
#define NH 4
#define ALPHA 0.2f
#define LDA 272                      // GEMM LDS row stride in bytes

#define BSH 9
#define BINW 512                     // nodes per bin
#define NBIN ((NN + BINW - 1) / BINW)   // 196
#define EPT 16                       // edges per thread, partition kernels
#define EPB (256 * EPT)              // 4096 edges per block
#define NPB1 ((NE + EPB - 1) / EPB)  // 391 blocks
#define CAP2 12288                   // LDS staging capacity in k_part2

typedef __bf16 bf16x8 __attribute__((ext_vector_type(8)));
typedef float f32x4 __attribute__((ext_vector_type(4)));

__device__ __forceinline__ float lrelu(float x) {
    return x > 0.0f ? x : ALPHA * x;
}
__device__ __forceinline__ unsigned short f2bf(float f) {
    __hip_bfloat16 b = __float2bfloat16(f);
    unsigned short u; memcpy(&u, &b, 2); return u;
}

// MFMA GEMM: h = x @ W, bf16 inputs (converted on the fly), fp32 accum, bf16 out.
__global__ __launch_bounds__(256) void k_gemm(
    const float* __restrict__ x, const float* __restrict__ W,
    __hip_bfloat16* __restrict__ hb) {
    __shared__ __align__(16) char sA[64 * LDA];    // x tile, bf16 [64][128]
    __shared__ __align__(16) char sB[128 * LDA];   // Wt, bf16 [col][k]
    const int tid = threadIdx.x;
    const int rowBase = blockIdx.x * 64;

    {
        union { uint2 d; unsigned short u[4]; } pk;
        for (int j = 0; j < 8; ++j) {
            const int i4 = tid + j * 256;
            const int r = i4 >> 5, c4 = i4 & 31;
            const int g = rowBase + r;
            float4 v = make_float4(0.f, 0.f, 0.f, 0.f);
            if (g < NN) v = *(const float4*)&x[(size_t)g * INF_ + c4 * 4];
            pk.u[0] = f2bf(v.x); pk.u[1] = f2bf(v.y);
            pk.u[2] = f2bf(v.z); pk.u[3] = f2bf(v.w);
            *(uint2*)(sA + r * LDA + c4 * 8) = pk.d;
        }
    }
    {
        const int c = tid & 127, kh = tid >> 7;
        union { uint4 q; unsigned short u[8]; } pk;
        for (int kb = 0; kb < 8; ++kb) {
            const int k0 = kh * 64 + kb * 8;
#pragma unroll
            for (int j = 0; j < 8; ++j)
                pk.u[j] = f2bf(W[(size_t)(k0 + j) * OC + c]);
            *(uint4*)(sB + c * LDA + k0 * 2) = pk.q;
        }
    }
    __syncthreads();

    const int lane = tid & 63;
    const int w = tid >> 6;
    const int arow = w * 16 + (lane & 15);
    const int koff = (lane >> 4) * 16;

    f32x4 acc[8];
#pragma unroll
    for (int n = 0; n < 8; ++n) acc[n] = (f32x4){0.f, 0.f, 0.f, 0.f};

#pragma unroll
    for (int kk = 0; kk < 4; ++kk) {
        const bf16x8 a = *(const bf16x8*)(sA + arow * LDA + kk * 64 + koff);
#pragma unroll
        for (int n = 0; n < 8; ++n) {
            const int brow = n * 16 + (lane & 15);
            const bf16x8 b = *(const bf16x8*)(sB + brow * LDA + kk * 64 + koff);
            acc[n] = __builtin_amdgcn_mfma_f32_16x16x32_bf16(a, b, acc[n], 0, 0, 0);
        }
    }

    const int rbase = rowBase + w * 16 + (lane >> 4) * 4;
#pragma unroll
    for (int n = 0; n < 8; ++n) {
        const int col = n * 16 + (lane & 15);
#pragma unroll
        for (int r = 0; r < 4; ++r) {
            const int row = rbase + r;
            if (row < NN) hb[(size_t)row * OC + col] = __float2bfloat16(acc[n][r]);
        }
    }
}

// Per-(node, head) attention halves from bf16 h.
__global__ __launch_bounds__(256) void k_att(
    const __hip_bfloat16* __restrict__ hb,
    const float* __restrict__ a_l, const float* __restrict__ a_r,
    float* __restrict__ al, float* __restrict__ ar) {
    const int t = blockIdx.x * 256 + threadIdx.x;
    if (t >= NN * NH) return;
    const int n = t >> 2, hd = t & 3;
    const uint4* hp = (const uint4*)((const char*)hb + (size_t)n * 256 + hd * 64);
    const float* alc = a_l + hd * 32;
    const float* arc = a_r + hd * 32;
    float sl = 0.f, sr = 0.f;
#pragma unroll
    for (int q = 0; q < 4; ++q) {
        const uint4 v = hp[q];
        const unsigned uu[4] = {v.x, v.y, v.z, v.w};
#pragma unroll
        for (int i = 0; i < 4; ++i) {
            const int k = q * 8 + i * 2;
            const float lo = __uint_as_float(uu[i] << 16);
            const float hi = __uint_as_float(uu[i] & 0xffff0000u);
            sl += lo * alc[k] + hi * alc[k + 1];
            sr += lo * arc[k] + hi * arc[k + 1];
        }
    }
    al[t] = sl;
    ar[t] = sr;
}

// Per-bin edge counts (LDS pre-aggregated).
__global__ __launch_bounds__(256) void k_binhist(
    const int* __restrict__ row, int* __restrict__ bincnt) {
    __shared__ int h[NBIN];
    const int t = threadIdx.x;
    for (int i = t; i < NBIN; i += 256) h[i] = 0;
    __syncthreads();
    const int base = blockIdx.x * EPB;
    for (int i = 0; i < EPT; ++i) {
        const int e = base + t + i * 256;
        if (e < NE) atomicAdd(&h[row[e] >> BSH], 1);
    }
    __syncthreads();
    for (int i = t; i < NBIN; i += 256)
        if (h[i]) atomicAdd(&bincnt[i], h[i]);
}

// Serial scan of bin counts -> binoffs, bincur; also offs[NN].
__global__ void k_binscan(const int* __restrict__ bincnt,
                          int* __restrict__ binoffs, int* __restrict__ bincur,
                          int* __restrict__ offs) {
    if (threadIdx.x == 0) {
        int acc = 0;
        for (int i = 0; i < NBIN; ++i) {
            binoffs[i] = acc; bincur[i] = acc; acc += bincnt[i];
        }
        binoffs[NBIN] = acc;   // == NE
        offs[NN] = NE;
    }
}

// Coarse partition: edges -> bin-grouped packed words ((r&511)<<17 | c).
__global__ __launch_bounds__(256) void k_part1(
    const int* __restrict__ row, const int* __restrict__ col,
    int* __restrict__ bincur, unsigned* __restrict__ tmp) {
    __shared__ int h[NBIN], gbase[NBIN], lcur[NBIN];
    const int t = threadIdx.x;
    for (int i = t; i < NBIN; i += 256) { h[i] = 0; lcur[i] = 0; }
    __syncthreads();

    const int e0 = blockIdx.x * EPB + t * EPT;
    int r[EPT], c[EPT];
    if (e0 + EPT <= NE) {
#pragma unroll
        for (int q = 0; q < EPT / 4; ++q) {
            const int4 rv = *(const int4*)&row[e0 + q * 4];
            const int4 cv = *(const int4*)&col[e0 + q * 4];
            r[q*4+0] = rv.x; r[q*4+1] = rv.y; r[q*4+2] = rv.z; r[q*4+3] = rv.w;
            c[q*4+0] = cv.x; c[q*4+1] = cv.y; c[q*4+2] = cv.z; c[q*4+3] = cv.w;
        }
    } else {
#pragma unroll
        for (int i = 0; i < EPT; ++i) {
            const int e = e0 + i;
            r[i] = (e < NE) ? row[e] : -1;
            c[i] = (e < NE) ? col[e] : 0;
        }
    }
#pragma unroll
    for (int i = 0; i < EPT; ++i)
        if (r[i] >= 0) atomicAdd(&h[r[i] >> BSH], 1);
    __syncthreads();
    for (int i = t; i < NBIN; i += 256)
        if (h[i]) gbase[i] = atomicAdd(&bincur[i], h[i]);
    __syncthreads();
#pragma unroll
    for (int i = 0; i < EPT; ++i) {
        if (r[i] < 0) continue;
        const int b = r[i] >> BSH;
        const int pos = atomicAdd(&lcur[b], 1);
        tmp[gbase[b] + pos] =
            ((unsigned)(r[i] & (BINW - 1)) << 17) | (unsigned)c[i];
    }
}

// Fine partition: one block per bin; emits node-sorted cols_s + per-node offs.
__global__ __launch_bounds__(256) void k_part2(
    const unsigned* __restrict__ tmp, const int* __restrict__ binoffs,
    int* __restrict__ offs, int* __restrict__ cols_s) {
    __shared__ unsigned stage[CAP2];          // 48 KB
    __shared__ int h[BINW], ps[256], cur[BINW];
    const int b = blockIdx.x, t = threadIdx.x;
    const int gs = binoffs[b], ge = binoffs[b + 1];
    const int cnt = ge - gs;
    for (int i = t; i < BINW; i += 256) h[i] = 0;
    __syncthreads();
    for (int j = t; j < cnt; j += 256) {
        const unsigned p = tmp[gs + j];
        if (j < CAP2) stage[j] = p;
        atomicAdd(&h[p >> 17], 1);
    }
    __syncthreads();
    const int a0 = h[2 * t], a1 = h[2 * t + 1];
    ps[t] = a0 + a1;
    __syncthreads();
    for (int o = 1; o < 256; o <<= 1) {
        const int add = (t >= o) ? ps[t - o] : 0;
        __syncthreads();
        ps[t] += add;
        __syncthreads();
    }
    const int ex = ps[t] - a0 - a1 + gs;
    cur[2 * t] = ex;
    cur[2 * t + 1] = ex + a0;
    const int node0 = b * BINW;
    if (node0 + 2 * t < NN)     offs[node0 + 2 * t]     = ex;
    if (node0 + 2 * t + 1 < NN) offs[node0 + 2 * t + 1] = ex + a0;
    __syncthreads();
    for (int j = t; j < cnt; j += 256) {
        const unsigned p = (j < CAP2) ? stage[j] : tmp[gs + j];
        const int pos = atomicAdd(&cur[p >> 17], 1);
        cols_s[pos] = (int)(p & 0x1FFFFu);
    }
}

// Fused score + softmax + aggregation, single pass: one wave per node.
// No max-subtraction: scores are bounded (|e| < ~15), exp is safe in fp32,
// and exp(e)/sum(exp(e)) == exp(e-m)/sum(exp(e-m)) exactly in the math.
__global__ __launch_bounds__(256) void k_agg(
    const int* __restrict__ offs, const int* __restrict__ cols_s,
    const float* __restrict__ al, const float* __restrict__ ar,
    const __hip_bfloat16* __restrict__ hb, float* __restrict__ out) {
    const int w = threadIdx.x >> 6;
    const int lane = threadIdx.x & 63;
    const int node = blockIdx.x * 4 + w;
    if (node >= NN) return;
    const int start = offs[node], end = offs[node + 1];
    const size_t loff = (size_t)(lane * 2);
    if (start == end) {
        *(float2*)&out[(size_t)node * OC + loff] = make_float2(0.f, 0.f);
        return;
    }
    const int hd = lane >> 4;          // head this lane accumulates
    const int sh = lane & 3;           // head this lane scores
    const int se = (lane >> 2) & 3;    // edge slot this lane scores
    const int sbase = (lane & 48) + hd;
    const float al_sh = al[node * NH + sh];

    float ssum = 0.f, accx = 0.f, accy = 0.f;
    int k = start;
    for (; k + 4 <= end; k += 4) {
        // lanes score (edge k+se, head sh); pattern replicated across 4 groups
        const int c = cols_s[k + se];
        const float wv = __expf(lrelu(al_sh + ar[c * NH + sh]));
        const int c0 = __shfl(c, 0), c1 = __shfl(c, 4);
        const int c2 = __shfl(c, 8), c3 = __shfl(c, 12);
        const float w0 = __shfl(wv, sbase);
        const float w1 = __shfl(wv, sbase + 4);
        const float w2 = __shfl(wv, sbase + 8);
        const float w3 = __shfl(wv, sbase + 12);
        const unsigned v0 = *(const unsigned*)&hb[(size_t)c0 * OC + loff];
        const unsigned v1 = *(const unsigned*)&hb[(size_t)c1 * OC + loff];
        const unsigned v2 = *(const unsigned*)&hb[(size_t)c2 * OC + loff];
        const unsigned v3 = *(const unsigned*)&hb[(size_t)c3 * OC + loff];
        accx += w0 * __uint_as_float(v0 << 16);
        accy += w0 * __uint_as_float(v0 & 0xffff0000u);
        accx += w1 * __uint_as_float(v1 << 16);
        accy += w1 * __uint_as_float(v1 & 0xffff0000u);
        accx += w2 * __uint_as_float(v2 << 16);
        accy += w2 * __uint_as_float(v2 & 0xffff0000u);
        accx += w3 * __uint_as_float(v3 << 16);
        accy += w3 * __uint_as_float(v3 & 0xffff0000u);
        ssum += (w0 + w1) + (w2 + w3);
    }
    if (k < end) {                     // tail: 1-3 edges
        const int rem = end - k;
        int c = 0; float wv = 0.f;
        if (se < rem) {
            c = cols_s[k + se];
            wv = __expf(lrelu(al_sh + ar[c * NH + sh]));
        }
        for (int j = 0; j < rem; ++j) {   // wave-uniform trip count
            const float wj = __shfl(wv, sbase + j * 4);
            const int cj = __shfl(c, j * 4);
            const unsigned v = *(const unsigned*)&hb[(size_t)cj * OC + loff];
            accx += wj * __uint_as_float(v << 16);
            accy += wj * __uint_as_float(v & 0xffff0000u);
            ssum += wj;
        }
    }
    const float inv = 1.0f / ssum;
    float2 o; o.x = accx * inv; o.y = accy * inv;
    *(float2*)&out[(size_t)node * OC + loff] = o;
}

extern "C" void kernel_launch(void* const* d_in, const int* in_sizes, int n_in,
                              void* d_out, int out_size, void* d_ws, size_t ws_size,
                              hipStream_t stream) {
    const float* x    = (const float*)d_in[0];
    const int*   ei   = (const int*)d_in[1];    // [2, NE]
    const float* W    = (const float*)d_in[2];
    const float* a_l  = (const float*)d_in[3];
    const float* a_r  = (const float*)d_in[4];
    float* out = (float*)d_out;

    const int* row = ei;         // destination
    const int* col = ei + NE;    // source

    char* ws = (char*)d_ws;
    __hip_bfloat16* hb = (__hip_bfloat16*)ws;   ws += (size_t)NN * OC * 2;   // 25.6 MB
    float*    al      = (float*)ws;             ws += (size_t)NN * NH * 4;
    float*    ar      = (float*)ws;             ws += (size_t)NN * NH * 4;
    int*      cols_s  = (int*)ws;               ws += (size_t)NE * 4;        // 6.4 MB
    unsigned* tmp     = (unsigned*)ws;          ws += (size_t)NE * 4;        // 6.4 MB
    int*      offs    = (int*)ws;               ws += (size_t)(NN + 1) * 4;
    int*      bincnt  = (int*)ws;               ws += (size_t)(NBIN + 1) * 4;
    int*      binoffs = (int*)ws;               ws += (size_t)(NBIN + 1) * 4;
    int*      bincur  = (int*)ws;               ws += (size_t)NBIN * 4;

    hipMemsetAsync(bincnt, 0, (size_t)NBIN * 4, stream);

    k_gemm<<<(NN + 63) / 64, 256, 0, stream>>>(x, W, hb);
    k_att<<<(NN * NH + 255) / 256, 256, 0, stream>>>(hb, a_l, a_r, al, ar);
    k_binhist<<<NPB1, 256, 0, stream>>>(row, bincnt);
    k_binscan<<<1, 64, 0, stream>>>(bincnt, binoffs, bincur, offs);
    k_part1<<<NPB1, 256, 0, stream>>>(row, col, bincur, tmp);
    k_part2<<<NBIN, 256, 0, stream>>>(tmp, binoffs, offs, cols_s);
    k_agg<<<(NN + 3) / 4, 256, 0, stream>>>(offs, cols_s, al, ar, hb, out);
}

// Round 8
// 188.744 us; speedup vs baseline: 1.7592x; 1.0201x over previous
//
#include <hip/hip_runtime.h>
#include <hip/hip_bf16.h>
#include <string.h>

#define NN 100000
#define NE 1600000
#define INF_ 128
#define OC 128   // NHEAD*OUT_F
#define NH 4
#define ALPHA 0.2f
#define LDA 272                      // GEMM LDS row stride in bytes

#define BSH 9
#define BINW 512                     // nodes per bin
#define NBIN ((NN + BINW - 1) / BINW)   // 196
#define EPT 16                       // edges per thread, partition kernels
#define EPB (256 * EPT)              // 4096 edges per block
#define NPB1 ((NE + EPB - 1) / EPB)  // 391 blocks
#define CAP2 12288                   // LDS staging capacity in k_part2

typedef __bf16 bf16x8 __attribute__((ext_vector_type(8)));
typedef float f32x4 __attribute__((ext_vector_type(4)));
typedef float f32x2 __attribute__((ext_vector_type(2)));

__device__ __forceinline__ float lrelu(float x) {
    return x > 0.0f ? x : ALPHA * x;
}
__device__ __forceinline__ unsigned short f2bf(float f) {
    __hip_bfloat16 b = __float2bfloat16(f);
    unsigned short u; memcpy(&u, &b, 2); return u;
}

// MFMA GEMM: h = x @ W, bf16 inputs (converted on the fly), fp32 accum, bf16 out.
__global__ __launch_bounds__(256) void k_gemm(
    const float* __restrict__ x, const float* __restrict__ W,
    __hip_bfloat16* __restrict__ hb) {
    __shared__ __align__(16) char sA[64 * LDA];    // x tile, bf16 [64][128]
    __shared__ __align__(16) char sB[128 * LDA];   // Wt, bf16 [col][k]
    const int tid = threadIdx.x;
    const int rowBase = blockIdx.x * 64;

    {
        union { uint2 d; unsigned short u[4]; } pk;
        for (int j = 0; j < 8; ++j) {
            const int i4 = tid + j * 256;
            const int r = i4 >> 5, c4 = i4 & 31;
            const int g = rowBase + r;
            float4 v = make_float4(0.f, 0.f, 0.f, 0.f);
            if (g < NN) v = *(const float4*)&x[(size_t)g * INF_ + c4 * 4];
            pk.u[0] = f2bf(v.x); pk.u[1] = f2bf(v.y);
            pk.u[2] = f2bf(v.z); pk.u[3] = f2bf(v.w);
            *(uint2*)(sA + r * LDA + c4 * 8) = pk.d;
        }
    }
    {
        const int c = tid & 127, kh = tid >> 7;
        union { uint4 q; unsigned short u[8]; } pk;
        for (int kb = 0; kb < 8; ++kb) {
            const int k0 = kh * 64 + kb * 8;
#pragma unroll
            for (int j = 0; j < 8; ++j)
                pk.u[j] = f2bf(W[(size_t)(k0 + j) * OC + c]);
            *(uint4*)(sB + c * LDA + k0 * 2) = pk.q;
        }
    }
    __syncthreads();

    const int lane = tid & 63;
    const int w = tid >> 6;
    const int arow = w * 16 + (lane & 15);
    const int koff = (lane >> 4) * 16;

    f32x4 acc[8];
#pragma unroll
    for (int n = 0; n < 8; ++n) acc[n] = (f32x4){0.f, 0.f, 0.f, 0.f};

#pragma unroll
    for (int kk = 0; kk < 4; ++kk) {
        const bf16x8 a = *(const bf16x8*)(sA + arow * LDA + kk * 64 + koff);
#pragma unroll
        for (int n = 0; n < 8; ++n) {
            const int brow = n * 16 + (lane & 15);
            const bf16x8 b = *(const bf16x8*)(sB + brow * LDA + kk * 64 + koff);
            acc[n] = __builtin_amdgcn_mfma_f32_16x16x32_bf16(a, b, acc[n], 0, 0, 0);
        }
    }

    const int rbase = rowBase + w * 16 + (lane >> 4) * 4;
#pragma unroll
    for (int n = 0; n < 8; ++n) {
        const int col = n * 16 + (lane & 15);
#pragma unroll
        for (int r = 0; r < 4; ++r) {
            const int row = rbase + r;
            if (row < NN) hb[(size_t)row * OC + col] = __float2bfloat16(acc[n][r]);
        }
    }
}

// Per-(node, head) attention halves from bf16 h.
__global__ __launch_bounds__(256) void k_att(
    const __hip_bfloat16* __restrict__ hb,
    const float* __restrict__ a_l, const float* __restrict__ a_r,
    float* __restrict__ al, float* __restrict__ ar) {
    const int t = blockIdx.x * 256 + threadIdx.x;
    if (t >= NN * NH) return;
    const int n = t >> 2, hd = t & 3;
    const uint4* hp = (const uint4*)((const char*)hb + (size_t)n * 256 + hd * 64);
    const float* alc = a_l + hd * 32;
    const float* arc = a_r + hd * 32;
    float sl = 0.f, sr = 0.f;
#pragma unroll
    for (int q = 0; q < 4; ++q) {
        const uint4 v = hp[q];
        const unsigned uu[4] = {v.x, v.y, v.z, v.w};
#pragma unroll
        for (int i = 0; i < 4; ++i) {
            const int k = q * 8 + i * 2;
            const float lo = __uint_as_float(uu[i] << 16);
            const float hi = __uint_as_float(uu[i] & 0xffff0000u);
            sl += lo * alc[k] + hi * alc[k + 1];
            sr += lo * arc[k] + hi * arc[k + 1];
        }
    }
    al[t] = sl;
    ar[t] = sr;
}

// Per-bin edge counts (LDS pre-aggregated).
__global__ __launch_bounds__(256) void k_binhist(
    const int* __restrict__ row, int* __restrict__ bincnt) {
    __shared__ int h[NBIN];
    const int t = threadIdx.x;
    for (int i = t; i < NBIN; i += 256) h[i] = 0;
    __syncthreads();
    const int base = blockIdx.x * EPB;
    for (int i = 0; i < EPT; ++i) {
        const int e = base + t + i * 256;
        if (e < NE) atomicAdd(&h[row[e] >> BSH], 1);
    }
    __syncthreads();
    for (int i = t; i < NBIN; i += 256)
        if (h[i]) atomicAdd(&bincnt[i], h[i]);
}

// Serial scan of bin counts -> binoffs, bincur; also offs[NN].
__global__ void k_binscan(const int* __restrict__ bincnt,
                          int* __restrict__ binoffs, int* __restrict__ bincur,
                          int* __restrict__ offs) {
    if (threadIdx.x == 0) {
        int acc = 0;
        for (int i = 0; i < NBIN; ++i) {
            binoffs[i] = acc; bincur[i] = acc; acc += bincnt[i];
        }
        binoffs[NBIN] = acc;   // == NE
        offs[NN] = NE;
    }
}

// Coarse partition: edges -> bin-grouped packed words ((r&511)<<17 | c).
__global__ __launch_bounds__(256) void k_part1(
    const int* __restrict__ row, const int* __restrict__ col,
    int* __restrict__ bincur, unsigned* __restrict__ tmp) {
    __shared__ int h[NBIN], gbase[NBIN], lcur[NBIN];
    const int t = threadIdx.x;
    for (int i = t; i < NBIN; i += 256) { h[i] = 0; lcur[i] = 0; }
    __syncthreads();

    const int e0 = blockIdx.x * EPB + t * EPT;
    int r[EPT], c[EPT];
    if (e0 + EPT <= NE) {
#pragma unroll
        for (int q = 0; q < EPT / 4; ++q) {
            const int4 rv = *(const int4*)&row[e0 + q * 4];
            const int4 cv = *(const int4*)&col[e0 + q * 4];
            r[q*4+0] = rv.x; r[q*4+1] = rv.y; r[q*4+2] = rv.z; r[q*4+3] = rv.w;
            c[q*4+0] = cv.x; c[q*4+1] = cv.y; c[q*4+2] = cv.z; c[q*4+3] = cv.w;
        }
    } else {
#pragma unroll
        for (int i = 0; i < EPT; ++i) {
            const int e = e0 + i;
            r[i] = (e < NE) ? row[e] : -1;
            c[i] = (e < NE) ? col[e] : 0;
        }
    }
#pragma unroll
    for (int i = 0; i < EPT; ++i)
        if (r[i] >= 0) atomicAdd(&h[r[i] >> BSH], 1);
    __syncthreads();
    for (int i = t; i < NBIN; i += 256)
        if (h[i]) gbase[i] = atomicAdd(&bincur[i], h[i]);
    __syncthreads();
#pragma unroll
    for (int i = 0; i < EPT; ++i) {
        if (r[i] < 0) continue;
        const int b = r[i] >> BSH;
        const int pos = atomicAdd(&lcur[b], 1);
        tmp[gbase[b] + pos] =
            ((unsigned)(r[i] & (BINW - 1)) << 17) | (unsigned)c[i];
    }
}

// Fine partition: one block per bin; emits node-sorted cols_s + per-node offs.
__global__ __launch_bounds__(256) void k_part2(
    const unsigned* __restrict__ tmp, const int* __restrict__ binoffs,
    int* __restrict__ offs, int* __restrict__ cols_s) {
    __shared__ unsigned stage[CAP2];          // 48 KB
    __shared__ int h[BINW], ps[256], cur[BINW];
    const int b = blockIdx.x, t = threadIdx.x;
    const int gs = binoffs[b], ge = binoffs[b + 1];
    const int cnt = ge - gs;
    for (int i = t; i < BINW; i += 256) h[i] = 0;
    __syncthreads();
    for (int j = t; j < cnt; j += 256) {
        const unsigned p = tmp[gs + j];
        if (j < CAP2) stage[j] = p;
        atomicAdd(&h[p >> 17], 1);
    }
    __syncthreads();
    const int a0 = h[2 * t], a1 = h[2 * t + 1];
    ps[t] = a0 + a1;
    __syncthreads();
    for (int o = 1; o < 256; o <<= 1) {
        const int add = (t >= o) ? ps[t - o] : 0;
        __syncthreads();
        ps[t] += add;
        __syncthreads();
    }
    const int ex = ps[t] - a0 - a1 + gs;
    cur[2 * t] = ex;
    cur[2 * t + 1] = ex + a0;
    const int node0 = b * BINW;
    if (node0 + 2 * t < NN)     offs[node0 + 2 * t]     = ex;
    if (node0 + 2 * t + 1 < NN) offs[node0 + 2 * t + 1] = ex + a0;
    __syncthreads();
    for (int j = t; j < cnt; j += 256) {
        const unsigned p = (j < CAP2) ? stage[j] : tmp[gs + j];
        const int pos = atomicAdd(&cur[p >> 17], 1);
        cols_s[pos] = (int)(p & 0x1FFFFu);
    }
}

// Fused score + softmax + aggregation: 16-lane group per node, 4 nodes/wave.
// Lane sl owns output dims [sl*8, sl*8+8) (one head, hsel = sl>>2) and loads
// its 16B slice of each gathered h row as one dwordx4.
__global__ __launch_bounds__(256) void k_agg(
    const int* __restrict__ offs, const int* __restrict__ cols_s,
    const float* __restrict__ al, const float* __restrict__ ar,
    const __hip_bfloat16* __restrict__ hb, float* __restrict__ out) {
    const int w = threadIdx.x >> 6;
    const int lane = threadIdx.x & 63;
    const int g = lane >> 4;            // node slot within wave
    const int sl = lane & 15;           // sublane within group
    const int node = blockIdx.x * 16 + w * 4 + g;
    const bool valid = node < NN;

    int start = 0, deg = 0;
    if (valid) {
        start = offs[node];
        deg = offs[node + 1] - start;
    }
    const int je = sl >> 2;             // edge slot this lane scores (= hsel)
    const int sh = sl & 3;              // head this lane scores
    const int hsel = je;                // head this lane accumulates
    const int sbase = lane & 48;        // group base lane
    const float al_sh = valid ? al[node * NH + sh] : 0.f;
    const char* hrow = (const char*)hb + sl * 16;   // lane's 16B slice

    f32x2 a0 = {0.f, 0.f}, a1 = {0.f, 0.f}, a2 = {0.f, 0.f}, a3 = {0.f, 0.f};
    float ssum = 0.f;

    for (int kk = 0; __any(kk < deg); kk += 4) {
        int c = 0; float wv = 0.f;
        const int kj = kk + je;
        if (kj < deg) {
            c = cols_s[start + kj];
            wv = __expf(lrelu(al_sh + ar[c * NH + sh]));
        }
#pragma unroll
        for (int j = 0; j < 4; ++j) {
            const float wj = __shfl(wv, sbase + j * 4 + hsel);
            const int   cj = __shfl(c,  sbase + j * 4);
            const uint4 v = *(const uint4*)(hrow + (size_t)cj * 256);
            const f32x2 p0 = {__uint_as_float(v.x << 16), __uint_as_float(v.x & 0xffff0000u)};
            const f32x2 p1 = {__uint_as_float(v.y << 16), __uint_as_float(v.y & 0xffff0000u)};
            const f32x2 p2 = {__uint_as_float(v.z << 16), __uint_as_float(v.z & 0xffff0000u)};
            const f32x2 p3 = {__uint_as_float(v.w << 16), __uint_as_float(v.w & 0xffff0000u)};
            a0 += wj * p0;
            a1 += wj * p1;
            a2 += wj * p2;
            a3 += wj * p3;
            ssum += wj;
        }
    }

    if (valid) {
        const float inv = (ssum > 0.f) ? 1.0f / ssum : 0.f;
        float4 o0, o1;
        o0.x = a0.x * inv; o0.y = a0.y * inv; o0.z = a1.x * inv; o0.w = a1.y * inv;
        o1.x = a2.x * inv; o1.y = a2.y * inv; o1.z = a3.x * inv; o1.w = a3.y * inv;
        float* dst = out + (size_t)node * OC + sl * 8;
        *(float4*)dst = o0;
        *(float4*)(dst + 4) = o1;
    }
}

extern "C" void kernel_launch(void* const* d_in, const int* in_sizes, int n_in,
                              void* d_out, int out_size, void* d_ws, size_t ws_size,
                              hipStream_t stream) {
    const float* x    = (const float*)d_in[0];
    const int*   ei   = (const int*)d_in[1];    // [2, NE]
    const float* W    = (const float*)d_in[2];
    const float* a_l  = (const float*)d_in[3];
    const float* a_r  = (const float*)d_in[4];
    float* out = (float*)d_out;

    const int* row = ei;         // destination
    const int* col = ei + NE;    // source

    char* ws = (char*)d_ws;
    __hip_bfloat16* hb = (__hip_bfloat16*)ws;   ws += (size_t)NN * OC * 2;   // 25.6 MB
    float*    al      = (float*)ws;             ws += (size_t)NN * NH * 4;
    float*    ar      = (float*)ws;             ws += (size_t)NN * NH * 4;
    int*      cols_s  = (int*)ws;               ws += (size_t)NE * 4;        // 6.4 MB
    unsigned* tmp     = (unsigned*)ws;          ws += (size_t)NE * 4;        // 6.4 MB
    int*      offs    = (int*)ws;               ws += (size_t)(NN + 1) * 4;
    int*      bincnt  = (int*)ws;               ws += (size_t)(NBIN + 1) * 4;
    int*      binoffs = (int*)ws;               ws += (size_t)(NBIN + 1) * 4;
    int*      bincur  = (int*)ws;               ws += (size_t)NBIN * 4;

    hipMemsetAsync(bincnt, 0, (size_t)NBIN * 4, stream);

    k_gemm<<<(NN + 63) / 64, 256, 0, stream>>>(x, W, hb);
    k_att<<<(NN * NH + 255) / 256, 256, 0, stream>>>(hb, a_l, a_r, al, ar);
    k_binhist<<<NPB1, 256, 0, stream>>>(row, bincnt);
    k_binscan<<<1, 64, 0, stream>>>(bincnt, binoffs, bincur, offs);
    k_part1<<<NPB1, 256, 0, stream>>>(row, col, bincur, tmp);
    k_part2<<<NBIN, 256, 0, stream>>>(tmp, binoffs, offs, cols_s);
    k_agg<<<(NN + 15) / 16, 256, 0, stream>>>(offs, cols_s, al, ar, hb, out);
}